// Round 12
// baseline (293.766 us; speedup 1.0000x reference)
//
#include <hip/hip_runtime.h>

#define CH 128           // feature channels (CIN == COUT == 128)
#define GEMM_BM 128      // rows per GEMM block
#define KSTEP 32         // K chunk per MFMA stage
#define LDP 40           // LDS row pitch in bf16 elems (80B -> 2-way max on b128 reads)
#define NBIN 1024        // degree bins for node counting sort
#define DSTR 16          // degree counter stride (1 per 64B line: kills same-line atomic serialization)

typedef __attribute__((ext_vector_type(8))) short bf16x8;
typedef __attribute__((ext_vector_type(4))) float f32x4;

static __device__ __forceinline__ unsigned short f2bf(float f) {
    unsigned int u = __float_as_uint(f);
    unsigned int r = (u + 0x7FFFu + ((u >> 16) & 1u)) >> 16;
    return (unsigned short)r;
}
static __device__ __forceinline__ float bflo(unsigned int v) {
    return __uint_as_float(v << 16);
}
static __device__ __forceinline__ float bfhi(unsigned int v) {
    return __uint_as_float(v & 0xffff0000u);
}

// ---------------------------------------------------------------- setup ----

// fused: degree histogram + rank  |  weight convert.
// deg counters strided DSTR apart (one per 64B line).
__global__ void setup1_k(const int* __restrict__ dst, int* __restrict__ deg,
                         int* __restrict__ rank, int E,
                         const float* __restrict__ w1, const float* __restrict__ w2,
                         const float* __restrict__ w3, short* __restrict__ Wt,
                         int wtotal, int histBlocks) {
    if ((int)blockIdx.x < histBlocks) {
        int e = blockIdx.x * 256 + threadIdx.x;
        if (e < E) rank[e] = atomicAdd(&deg[dst[e] * DSTR], 1);
    } else {
        int idx = ((int)blockIdx.x - histBlocks) * 256 + threadIdx.x;
        if (idx >= wtotal) return;
        int p = idx >> 14;
        int k = (idx >> 7) & 127;
        int c = idx & 127;
        float v;
        if (p == 0)      v = w1[idx];
        else if (p <= 3) v = w2[idx - (1 << 14)];
        else             v = w3[idx - (4 << 14)];
        Wt[(p << 14) + (c << 7) + k] = (short)f2bf(v);
    }
}

// block-local exclusive scan of deg -> rowptr; also degree-bin histogram
__global__ __launch_bounds__(1024) void scan_partial_k(const int* __restrict__ deg,
                                                       int* __restrict__ rowptr,
                                                       int* __restrict__ bsum,
                                                       int* __restrict__ bins, int N) {
    __shared__ int sm[1024];
    __shared__ int lb[NBIN];
    int t = threadIdx.x;
    lb[t] = 0;
    int i = blockIdx.x * 1024 + t;
    int v = (i < N) ? deg[i * DSTR] : 0;
    sm[t] = v;
    __syncthreads();
    if (i < N) atomicAdd(&lb[v & (NBIN - 1)], 1);
    int x = v;
    for (int off = 1; off < 1024; off <<= 1) {
        int y = (t >= off) ? sm[t - off] : 0;
        __syncthreads();
        x += y;
        sm[t] = x;
        __syncthreads();
    }
    if (i < N) rowptr[i] = x - v;          // block-local exclusive
    if (t == 1023) bsum[blockIdx.x] = x;   // block total
    if (lb[t]) atomicAdd(&bins[t], lb[t]);
}

// add block offsets to rowptr; block 0 also exclusive-scans the degree bins
__global__ __launch_bounds__(1024) void scan_add2_k(int* __restrict__ rowptr,
                                                    const int* __restrict__ bsum,
                                                    int nb, int N,
                                                    const int* __restrict__ bins,
                                                    int* __restrict__ binofs) {
    __shared__ int soff;
    __shared__ int bs[NBIN];
    int t = threadIdx.x;
    if (t == 0) {
        int run = 0;
        for (int b = 0; b < (int)blockIdx.x; ++b) run += bsum[b];
        soff = run;
        if ((int)blockIdx.x == nb - 1) {
            int tot = run;
            for (int b = blockIdx.x; b < nb; ++b) tot += bsum[b];
            rowptr[N] = tot;   // == E
        }
    }
    if (blockIdx.x == 0) {
        int v = bins[t];
        bs[t] = v;
        __syncthreads();
        int x = v;
        for (int off = 1; off < NBIN; off <<= 1) {
            int y = (t >= off) ? bs[t - off] : 0;
            __syncthreads();
            x += y;
            bs[t] = x;
            __syncthreads();
        }
        binofs[t] = x - v;
    }
    __syncthreads();
    int i = blockIdx.x * 1024 + t;
    if (i < N) rowptr[i] += soff;
}

// fused: CSR fill (atomic-free; rank precomputed)  |  degree-sort perm
__global__ __launch_bounds__(1024) void setup2_k(const int* __restrict__ src,
                                                 const int* __restrict__ dst,
                                                 const int* __restrict__ rank,
                                                 const int* __restrict__ rowptr,
                                                 const int* __restrict__ deg,
                                                 int2* __restrict__ csw, int E,
                                                 const int* __restrict__ binofs,
                                                 int* __restrict__ binfill,
                                                 int* __restrict__ perm, int M,
                                                 int fillBlocks) {
    if ((int)blockIdx.x < fillBlocks) {
        int e = blockIdx.x * 1024 + threadIdx.x;
        if (e >= E) return;
        int s = src[e], d = dst[e];
        int ds_ = deg[s * DSTR], dd = deg[d * DSTR];
        float dis = (ds_ > 0) ? rsqrtf((float)ds_) : 0.f;
        float did = (dd  > 0) ? rsqrtf((float)dd)  : 0.f;
        csw[rowptr[d] + rank[e]] = make_int2(s, __float_as_int(-dis * did));
    } else {
        __shared__ int lb[NBIN];
        __shared__ int lbase[NBIN];
        int t = threadIdx.x;
        lb[t] = 0;
        __syncthreads();
        int n = ((int)blockIdx.x - fillBlocks) * 1024 + t;
        int v = 0, r = 0;
        if (n < M) {
            v = deg[n * DSTR] & (NBIN - 1);
            r = atomicAdd(&lb[v], 1);          // local rank within (block, bin)
        }
        __syncthreads();
        if (lb[t] > 0) lbase[t] = atomicAdd(&binfill[t], lb[t]);   // block base
        __syncthreads();
        if (n < M) perm[binofs[v] + lbase[v] + r] = n;
    }
}

// ---------------------------------------------------------------- prop -----
// bf16 features: row = 128 bf16 = 16 uint4. 16 lanes per node, uint4/lane.
// 4 nodes per wave, 4-wide unroll -> 16 gathers in flight per wave.
// Degree-sorted order (perm): uniform trip counts across lanes.

__global__ __launch_bounds__(256) void prop_k(const uint4* __restrict__ xin,
                                              const int* __restrict__ rowptr,
                                              const int2* __restrict__ csw,
                                              const int* __restrict__ perm,
                                              const uint4* __restrict__ other,
                                              float alpha, float beta,
                                              uint4* __restrict__ out, int M) {
    int gidx = (blockIdx.x * 256 + threadIdx.x) >> 4;   // sorted position
    if (gidx >= M) return;
    int g = perm[gidx];                                  // node index
    int lane = threadIdx.x & 15;                         // sub-row 16B chunk
    int e0 = rowptr[g], e1 = rowptr[g + 1];
    float a0[8], a1[8];
    #pragma unroll
    for (int c = 0; c < 8; ++c) { a0[c] = 0.f; a1[c] = 0.f; }

    int e = e0;
    for (; e + 4 <= e1; e += 4) {
        int2 p0 = csw[e], p1 = csw[e + 1], p2 = csw[e + 2], p3 = csw[e + 3];
        uint4 v0 = xin[(size_t)p0.x * 16 + lane];
        uint4 v1 = xin[(size_t)p1.x * 16 + lane];
        uint4 v2 = xin[(size_t)p2.x * 16 + lane];
        uint4 v3 = xin[(size_t)p3.x * 16 + lane];
        float w0 = __int_as_float(p0.y), w1 = __int_as_float(p1.y);
        float w2 = __int_as_float(p2.y), w3 = __int_as_float(p3.y);
        a0[0] = fmaf(w0, bflo(v0.x), a0[0]); a0[1] = fmaf(w0, bfhi(v0.x), a0[1]);
        a0[2] = fmaf(w0, bflo(v0.y), a0[2]); a0[3] = fmaf(w0, bfhi(v0.y), a0[3]);
        a0[4] = fmaf(w0, bflo(v0.z), a0[4]); a0[5] = fmaf(w0, bfhi(v0.z), a0[5]);
        a0[6] = fmaf(w0, bflo(v0.w), a0[6]); a0[7] = fmaf(w0, bfhi(v0.w), a0[7]);
        a1[0] = fmaf(w1, bflo(v1.x), a1[0]); a1[1] = fmaf(w1, bfhi(v1.x), a1[1]);
        a1[2] = fmaf(w1, bflo(v1.y), a1[2]); a1[3] = fmaf(w1, bfhi(v1.y), a1[3]);
        a1[4] = fmaf(w1, bflo(v1.z), a1[4]); a1[5] = fmaf(w1, bfhi(v1.z), a1[5]);
        a1[6] = fmaf(w1, bflo(v1.w), a1[6]); a1[7] = fmaf(w1, bfhi(v1.w), a1[7]);
        a0[0] = fmaf(w2, bflo(v2.x), a0[0]); a0[1] = fmaf(w2, bfhi(v2.x), a0[1]);
        a0[2] = fmaf(w2, bflo(v2.y), a0[2]); a0[3] = fmaf(w2, bfhi(v2.y), a0[3]);
        a0[4] = fmaf(w2, bflo(v2.z), a0[4]); a0[5] = fmaf(w2, bfhi(v2.z), a0[5]);
        a0[6] = fmaf(w2, bflo(v2.w), a0[6]); a0[7] = fmaf(w2, bfhi(v2.w), a0[7]);
        a1[0] = fmaf(w3, bflo(v3.x), a1[0]); a1[1] = fmaf(w3, bfhi(v3.x), a1[1]);
        a1[2] = fmaf(w3, bflo(v3.y), a1[2]); a1[3] = fmaf(w3, bfhi(v3.y), a1[3]);
        a1[4] = fmaf(w3, bflo(v3.z), a1[4]); a1[5] = fmaf(w3, bfhi(v3.z), a1[5]);
        a1[6] = fmaf(w3, bflo(v3.w), a1[6]); a1[7] = fmaf(w3, bfhi(v3.w), a1[7]);
    }
    for (; e < e1; ++e) {
        int2 p0 = csw[e];
        uint4 v0 = xin[(size_t)p0.x * 16 + lane];
        float w0 = __int_as_float(p0.y);
        a0[0] = fmaf(w0, bflo(v0.x), a0[0]); a0[1] = fmaf(w0, bfhi(v0.x), a0[1]);
        a0[2] = fmaf(w0, bflo(v0.y), a0[2]); a0[3] = fmaf(w0, bfhi(v0.y), a0[3]);
        a0[4] = fmaf(w0, bflo(v0.z), a0[4]); a0[5] = fmaf(w0, bfhi(v0.z), a0[5]);
        a0[6] = fmaf(w0, bflo(v0.w), a0[6]); a0[7] = fmaf(w0, bfhi(v0.w), a0[7]);
    }

    float r[8];
    #pragma unroll
    for (int c = 0; c < 8; ++c) r[c] = alpha * (a0[c] + a1[c]);
    if (beta != 0.f) {
        uint4 o = other[(size_t)g * 16 + lane];
        r[0] = fmaf(beta, bflo(o.x), r[0]); r[1] = fmaf(beta, bfhi(o.x), r[1]);
        r[2] = fmaf(beta, bflo(o.y), r[2]); r[3] = fmaf(beta, bfhi(o.y), r[3]);
        r[4] = fmaf(beta, bflo(o.z), r[4]); r[5] = fmaf(beta, bfhi(o.z), r[5]);
        r[6] = fmaf(beta, bflo(o.w), r[6]); r[7] = fmaf(beta, bfhi(o.w), r[7]);
    }
    uint4 ov;
    ov.x = (unsigned int)f2bf(r[0]) | ((unsigned int)f2bf(r[1]) << 16);
    ov.y = (unsigned int)f2bf(r[2]) | ((unsigned int)f2bf(r[3]) << 16);
    ov.z = (unsigned int)f2bf(r[4]) | ((unsigned int)f2bf(r[5]) << 16);
    ov.w = (unsigned int)f2bf(r[6]) | ((unsigned int)f2bf(r[7]) << 16);
    out[(size_t)g * 16 + lane] = ov;
}

// ---------------------------------------------------------------- GEMM -----
// MFMA bf16 GEMM: C[m0:m0+128][0:128] = sum_{p<nP} A_p @ W_p (+ bias)
// A is never LDS-staged: each A row feeds exactly ONE wave, and the
// 16x16x32 A-fragment (row = ..+lh, 8 contiguous k per lane) is a
// full-64B-line coalesced global load (lanes 0..63 = 16 rows x 4 k-chunks).
// Only B (reused by all 4 waves) is LDS-staged, once per piece.
// LDS 40KB -> 4 blocks/CU (~16 waves/CU, 2x the old occupancy).
// ABF:   A is bf16 (else fp32, converted in registers).
// STATS: fused per-column BatchNorm sum/sumsq (fp32, pre-rounding) -> sums.
// OBF:   write C as bf16.

template<bool ABF, bool STATS, bool OBF>
__global__ __launch_bounds__(256) void gemm_k(const void* __restrict__ A0_,
                                              const void* __restrict__ A1_,
                                              const void* __restrict__ A2_,
                                              const void* __restrict__ A3_,
                                              const void* __restrict__ A4_,
                                              const short* __restrict__ Wt,
                                              const float* __restrict__ bias,
                                              void* __restrict__ C_,
                                              float* __restrict__ sums,
                                              int M, int nP) {
    __shared__ short Bs[4][128 * LDP];   // whole piece of B [k-tile][col][k]
    int t = threadIdx.x;
    int m0 = blockIdx.x * GEMM_BM;
    int wave = t >> 6;
    int lane = t & 63;
    int lh = lane & 15;        // fragment row/col within 16
    int kq = lane >> 4;        // k-group 0..3

    f32x4 acc[2][8];
    #pragma unroll
    for (int i = 0; i < 2; ++i)
        #pragma unroll
        for (int j = 0; j < 8; ++j) acc[i][j] = (f32x4){0.f, 0.f, 0.f, 0.f};

    const void* Aps[5] = {A0_, A1_, A2_, A3_, A4_};
    int srow = t >> 1;                 // B staging col 0..127
    int skh  = (t & 1) << 4;           // B staging k offset 0 or 16

    int rowA[2]; bool okA[2];
    #pragma unroll
    for (int fm = 0; fm < 2; ++fm) {
        rowA[fm] = m0 + wave * 32 + fm * 16 + lh;
        okA[fm] = rowA[fm] < M;
    }

    for (int p = 0; p < nP; ++p) {
        __syncthreads();   // previous piece's Bs reads complete
        const short* Wp = Wt + ((size_t)p << 14);
        #pragma unroll
        for (int kt = 0; kt < 4; ++kt) {
            const bf16x8* srcB = (const bf16x8*)&Wp[(srow << 7) + kt * KSTEP + skh];
            *(bf16x8*)&Bs[kt][srow * LDP + skh]     = srcB[0];
            *(bf16x8*)&Bs[kt][srow * LDP + skh + 8] = srcB[1];
        }
        __syncthreads();
        // ---- load this piece's A fragments straight from global
        bf16x8 af[4][2];
        #pragma unroll
        for (int k = 0; k < 4; ++k) {
            #pragma unroll
            for (int fm = 0; fm < 2; ++fm) {
                af[k][fm] = (bf16x8){0,0,0,0,0,0,0,0};
                if (okA[fm]) {
                    if (ABF) {
                        af[k][fm] = *(const bf16x8*)
                            &((const unsigned short*)Aps[p])[(size_t)rowA[fm] * CH + k * KSTEP + kq * 8];
                    } else {
                        const float* s = &((const float*)Aps[p])[(size_t)rowA[fm] * CH + k * KSTEP + kq * 8];
                        float4 x0 = *(const float4*)s;
                        float4 x1 = *(const float4*)(s + 4);
                        bf16x8 v;
                        v[0] = (short)f2bf(x0.x); v[1] = (short)f2bf(x0.y);
                        v[2] = (short)f2bf(x0.z); v[3] = (short)f2bf(x0.w);
                        v[4] = (short)f2bf(x1.x); v[5] = (short)f2bf(x1.y);
                        v[6] = (short)f2bf(x1.z); v[7] = (short)f2bf(x1.w);
                        af[k][fm] = v;
                    }
                }
            }
        }
        // ---- 4 K-steps, barrier-free
        #pragma unroll
        for (int k = 0; k < 4; ++k) {
            bf16x8 bfr[8];
            #pragma unroll
            for (int fn = 0; fn < 8; ++fn)
                bfr[fn] = *(const bf16x8*)&Bs[k][(fn * 16 + lh) * LDP + kq * 8];
            #pragma unroll
            for (int fm = 0; fm < 2; ++fm)
                #pragma unroll
                for (int fn = 0; fn < 8; ++fn)
                    acc[fm][fn] = __builtin_amdgcn_mfma_f32_16x16x32_bf16(
                        af[k][fm], bfr[fn], acc[fm][fn], 0, 0, 0);
        }
    }

    // ---- epilogue: row = m0 + wave*32 + fm*16 + kq*4 + j, col = fn*16 + lh
    float s_[8], q_[8];
    #pragma unroll
    for (int fn = 0; fn < 8; ++fn) { s_[fn] = 0.f; q_[fn] = 0.f; }
    float bj[8];
    #pragma unroll
    for (int fn = 0; fn < 8; ++fn) bj[fn] = bias ? bias[fn * 16 + lh] : 0.f;

    #pragma unroll
    for (int fm = 0; fm < 2; ++fm) {
        #pragma unroll
        for (int j = 0; j < 4; ++j) {
            int m = m0 + wave * 32 + fm * 16 + kq * 4 + j;
            if (m >= M) continue;
            #pragma unroll
            for (int fn = 0; fn < 8; ++fn) {
                int col = fn * 16 + lh;
                float v = acc[fm][fn][j] + bj[fn];
                if (STATS) { s_[fn] += v; q_[fn] = fmaf(v, v, q_[fn]); }
                if (OBF) ((unsigned short*)C_)[(size_t)m * CH + col] = f2bf(v);
                else     ((float*)C_)[(size_t)m * CH + col] = v;
            }
        }
    }

    if (STATS) {
        #pragma unroll
        for (int fn = 0; fn < 8; ++fn) {
            s_[fn] += __shfl_xor(s_[fn], 16); s_[fn] += __shfl_xor(s_[fn], 32);
            q_[fn] += __shfl_xor(q_[fn], 16); q_[fn] += __shfl_xor(q_[fn], 32);
        }
        float* red = (float*)&Bs[0][0];   // reuse Bs LDS: [2][4][128] floats
        __syncthreads();                  // all waves done reading Bs
        if (kq == 0) {
            #pragma unroll
            for (int fn = 0; fn < 8; ++fn) {
                red[(0 * 4 + wave) * 128 + fn * 16 + lh] = s_[fn];
                red[(1 * 4 + wave) * 128 + fn * 16 + lh] = q_[fn];
            }
        }
        __syncthreads();
        if (t < 128) {
            float ss = red[0 * 128 + t] + red[1 * 128 + t] + red[2 * 128 + t] + red[3 * 128 + t];
            float qq = red[4 * 128 + t] + red[5 * 128 + t] + red[6 * 128 + t] + red[7 * 128 + t];
            atomicAdd(&sums[t], ss);
            atomicAdd(&sums[128 + t], qq);
        }
    }
}

// ---------------------------------------------------------------- BN -------
// BN coef computed per block from fused stats; apply + ReLU, bf16 -> bf16

__global__ __launch_bounds__(256) void bnapply_k(const unsigned int* __restrict__ hb,
                                                 const float* __restrict__ sums,
                                                 const float* __restrict__ gamma,
                                                 const float* __restrict__ beta,
                                                 float invM,
                                                 unsigned int* __restrict__ outb, int M) {
    __shared__ float sc[128], sh[128];
    int t = threadIdx.x;
    if (t < 128) {
        float m   = sums[t] * invM;
        float var = fmaxf(sums[128 + t] * invM - m * m, 0.f);
        float s   = gamma[t] * rsqrtf(var + 1e-5f);
        sc[t] = s;
        sh[t] = beta[t] - m * s;
    }
    __syncthreads();
    int total = M * 64;
    for (int idx = blockIdx.x * blockDim.x + t; idx < total;
         idx += gridDim.x * blockDim.x) {
        int c2 = (idx & 63) * 2;
        unsigned int v = hb[idx];
        float a = fmaxf(fmaf(bflo(v), sc[c2 + 0], sh[c2 + 0]), 0.f);
        float b = fmaxf(fmaf(bfhi(v), sc[c2 + 1], sh[c2 + 1]), 0.f);
        outb[idx] = (unsigned int)f2bf(a) | ((unsigned int)f2bf(b) << 16);
    }
}

// ---------------------------------------------------------------- launch ---

extern "C" void kernel_launch(void* const* d_in, const int* in_sizes, int n_in,
                              void* d_out, int out_size, void* d_ws, size_t ws_size,
                              hipStream_t stream) {
    const float* x      = (const float*)d_in[0];
    const int*   ei     = (const int*)d_in[1];
    const float* w1     = (const float*)d_in[2];
    const float* b1     = (const float*)d_in[3];
    const float* w2     = (const float*)d_in[4];
    const float* b2     = (const float*)d_in[5];
    const float* w3     = (const float*)d_in[6];
    const float* b3     = (const float*)d_in[7];
    const float* gamma1 = (const float*)d_in[8];
    const float* beta1  = (const float*)d_in[9];
    const float* gamma2 = (const float*)d_in[10];
    const float* beta2  = (const float*)d_in[11];
    float* out = (float*)d_out;

    const int M = in_sizes[0] / CH;   // 50000 nodes
    const int E = in_sizes[1] / 2;    // 600000 edges
    const int* srcp = ei;
    const int* dstp = ei + E;

    size_t off = 0;
    auto alloc = [&](size_t bytes) {
        void* p = (char*)d_ws + off;
        off += (bytes + 255) & ~(size_t)255;
        return p;
    };
    // zeroed-region first (one memset covers deg|bins|binfill|bnsumsA|bnsumsB)
    int*   degi    = (int*)  alloc((size_t)M * DSTR * 4);   // strided counters
    int*   bins    = (int*)  alloc(NBIN * 4);
    int*   binfill = (int*)  alloc(NBIN * 4);
    float* bnsumsA = (float*)alloc(1024);
    float* bnsumsB = (float*)alloc(1024);
    size_t zero_bytes = off;
    unsigned int* PB0 = (unsigned int*)alloc((size_t)M * CH * 2);  // bf16 feat
    unsigned int* PB1 = (unsigned int*)alloc((size_t)M * CH * 2);
    unsigned int* PB2 = (unsigned int*)alloc((size_t)M * CH * 2);
    unsigned int* PB3 = (unsigned int*)alloc((size_t)M * CH * 2);
    unsigned int* PB4 = (unsigned int*)alloc((size_t)M * CH * 2);
    unsigned int* Hb  = (unsigned int*)alloc((size_t)M * CH * 2);  // bf16 pre-BN
    int2*  csw     = (int2*) alloc((size_t)E * 8);
    int*   rank    = (int*)  alloc((size_t)E * 4);
    int*   rowptr  = (int*)  alloc((size_t)(M + 1) * 4);
    int*   bsum    = (int*)  alloc(4096);
    int*   binofs  = (int*)  alloc(NBIN * 4);
    int*   perm    = (int*)  alloc((size_t)M * 4);
    short* Wt      = (short*)alloc((size_t)9 * CH * CH * 2);       // 9 pieces
    (void)ws_size; (void)n_in; (void)out_size;

    const int nb = (M + 1023) / 1024;
    const int gb = (M + GEMM_BM - 1) / GEMM_BM;
    const int pgrid = (M + 15) / 16;   // 16 nodes per 256-thread block
    const int histBlocks = (E + 255) / 256;
    const int wBlocks = (9 * 16384 + 255) / 256;
    const int fillBlocks = (E + 1023) / 1024;

    // ---- graph setup: degree+rank+wconv -> rowptr(+bins) -> CSR+perm
    hipMemsetAsync(degi, 0, zero_bytes, stream);
    setup1_k<<<histBlocks + wBlocks, 256, 0, stream>>>(dstp, degi, rank, E,
                                                       w1, w2, w3, Wt, 9 * 16384,
                                                       histBlocks);
    scan_partial_k<<<nb, 1024, 0, stream>>>(degi, rowptr, bsum, bins, M);
    scan_add2_k<<<nb, 1024, 0, stream>>>(rowptr, bsum, nb, M, bins, binofs);
    setup2_k<<<fillBlocks + nb, 1024, 0, stream>>>(srcp, dstp, rank, rowptr, degi,
                                                   csw, E, binofs, binfill, perm, M,
                                                   fillBlocks);

    // ---- layer 1: Hb = bf16(x @ W1 + b1) (fp32 stats fused) ; BN+ReLU -> PB0
    gemm_k<false, true, true><<<gb, 256, 0, stream>>>(x, nullptr, nullptr, nullptr,
                                                      nullptr, Wt, b1, Hb, bnsumsA, M, 1);
    bnapply_k<<<2048, 256, 0, stream>>>(Hb, bnsumsA, gamma1, beta1, 1.f / (float)M, PB0, M);

    // ---- layer 2 (K=3): Tx0=PB0, Tx1=PB1, Tx2=PB2 ; BN+ReLU -> PB0
    prop_k<<<pgrid, 256, 0, stream>>>((const uint4*)PB0, rowptr, csw, perm,
                                      (const uint4*)PB0, 1.f, 0.f, (uint4*)PB1, M);
    prop_k<<<pgrid, 256, 0, stream>>>((const uint4*)PB1, rowptr, csw, perm,
                                      (const uint4*)PB0, 2.f, -1.f, (uint4*)PB2, M);
    gemm_k<true, true, true><<<gb, 256, 0, stream>>>(PB0, PB1, PB2, nullptr, nullptr,
                                                     Wt + (1 << 14), b2, Hb, bnsumsB, M, 3);
    bnapply_k<<<2048, 256, 0, stream>>>(Hb, bnsumsB, gamma2, beta2, 1.f / (float)M, PB0, M);

    // ---- layer 3 (K=5): Tx0=PB0 ... Tx4=PB4, single nP=5 GEMM -> out (fp32)
    prop_k<<<pgrid, 256, 0, stream>>>((const uint4*)PB0, rowptr, csw, perm,
                                      (const uint4*)PB0, 1.f, 0.f, (uint4*)PB1, M);
    prop_k<<<pgrid, 256, 0, stream>>>((const uint4*)PB1, rowptr, csw, perm,
                                      (const uint4*)PB0, 2.f, -1.f, (uint4*)PB2, M);
    prop_k<<<pgrid, 256, 0, stream>>>((const uint4*)PB2, rowptr, csw, perm,
                                      (const uint4*)PB1, 2.f, -1.f, (uint4*)PB3, M);
    prop_k<<<pgrid, 256, 0, stream>>>((const uint4*)PB3, rowptr, csw, perm,
                                      (const uint4*)PB2, 2.f, -1.f, (uint4*)PB4, M);
    gemm_k<true, false, false><<<gb, 256, 0, stream>>>(PB0, PB1, PB2, PB3, PB4,
                                                       Wt + (4 << 14), b3, out, nullptr, M, 5);
}

// Round 13
// 286.220 us; speedup vs baseline: 1.0264x; 1.0264x over previous
//
#include <hip/hip_runtime.h>

#define CH 128           // feature channels (CIN == COUT == 128)
#define GEMM_BM 128      // rows per GEMM block
#define KSTEP 32         // K chunk per MFMA stage
#define LDP 40           // LDS row pitch in bf16 elems (80B -> 2-way max on b128 reads)
#define NBIN 1024        // degree bins for node counting sort

typedef __attribute__((ext_vector_type(8))) short bf16x8;
typedef __attribute__((ext_vector_type(4))) float f32x4;

static __device__ __forceinline__ unsigned short f2bf(float f) {
    unsigned int u = __float_as_uint(f);
    unsigned int r = (u + 0x7FFFu + ((u >> 16) & 1u)) >> 16;
    return (unsigned short)r;
}
static __device__ __forceinline__ float bflo(unsigned int v) {
    return __uint_as_float(v << 16);
}
static __device__ __forceinline__ float bfhi(unsigned int v) {
    return __uint_as_float(v & 0xffff0000u);
}

// ---------------------------------------------------------------- setup ----

// fused: degree histogram + rank  |  weight convert (independent work,
// split by blockIdx range; saves a dispatch)
__global__ void setup1_k(const int* __restrict__ dst, int* __restrict__ deg,
                         int* __restrict__ rank, int E,
                         const float* __restrict__ w1, const float* __restrict__ w2,
                         const float* __restrict__ w3, short* __restrict__ Wt,
                         int wtotal, int histBlocks) {
    if ((int)blockIdx.x < histBlocks) {
        int e = blockIdx.x * 256 + threadIdx.x;
        if (e < E) rank[e] = atomicAdd(&deg[dst[e]], 1);
    } else {
        int idx = ((int)blockIdx.x - histBlocks) * 256 + threadIdx.x;
        if (idx >= wtotal) return;
        int p = idx >> 14;
        int k = (idx >> 7) & 127;
        int c = idx & 127;
        float v;
        if (p == 0)      v = w1[idx];
        else if (p <= 3) v = w2[idx - (1 << 14)];
        else             v = w3[idx - (4 << 14)];
        Wt[(p << 14) + (c << 7) + k] = (short)f2bf(v);
    }
}

// block-local exclusive scan of deg -> rowptr; also degree-bin histogram
__global__ __launch_bounds__(1024) void scan_partial_k(const int* __restrict__ deg,
                                                       int* __restrict__ rowptr,
                                                       int* __restrict__ bsum,
                                                       int* __restrict__ bins, int N) {
    __shared__ int sm[1024];
    __shared__ int lb[NBIN];
    int t = threadIdx.x;
    lb[t] = 0;
    int i = blockIdx.x * 1024 + t;
    int v = (i < N) ? deg[i] : 0;
    sm[t] = v;
    __syncthreads();
    if (i < N) atomicAdd(&lb[v & (NBIN - 1)], 1);
    int x = v;
    for (int off = 1; off < 1024; off <<= 1) {
        int y = (t >= off) ? sm[t - off] : 0;
        __syncthreads();
        x += y;
        sm[t] = x;
        __syncthreads();
    }
    if (i < N) rowptr[i] = x - v;          // block-local exclusive
    if (t == 1023) bsum[blockIdx.x] = x;   // block total
    if (lb[t]) atomicAdd(&bins[t], lb[t]);
}

// add block offsets to rowptr; block 0 also exclusive-scans the degree bins
__global__ __launch_bounds__(1024) void scan_add2_k(int* __restrict__ rowptr,
                                                    const int* __restrict__ bsum,
                                                    int nb, int N,
                                                    const int* __restrict__ bins,
                                                    int* __restrict__ binofs) {
    __shared__ int soff;
    __shared__ int bs[NBIN];
    int t = threadIdx.x;
    if (t == 0) {
        int run = 0;
        for (int b = 0; b < (int)blockIdx.x; ++b) run += bsum[b];
        soff = run;
        if ((int)blockIdx.x == nb - 1) {
            int tot = run;
            for (int b = blockIdx.x; b < nb; ++b) tot += bsum[b];
            rowptr[N] = tot;   // == E
        }
    }
    if (blockIdx.x == 0) {
        int v = bins[t];
        bs[t] = v;
        __syncthreads();
        int x = v;
        for (int off = 1; off < NBIN; off <<= 1) {
            int y = (t >= off) ? bs[t - off] : 0;
            __syncthreads();
            x += y;
            bs[t] = x;
            __syncthreads();
        }
        binofs[t] = x - v;
    }
    __syncthreads();
    int i = blockIdx.x * 1024 + t;
    if (i < N) rowptr[i] += soff;
}

// fused: CSR fill (atomic-free; rank precomputed)  |  degree-sort perm
// (two-level counting-sort: LDS ranks + one global atomic per block,bin).
// Both depend only on scan_add2; independent of each other.
__global__ __launch_bounds__(1024) void setup2_k(const int* __restrict__ src,
                                                 const int* __restrict__ dst,
                                                 const int* __restrict__ rank,
                                                 const int* __restrict__ rowptr,
                                                 const int* __restrict__ deg,
                                                 int2* __restrict__ csw, int E,
                                                 const int* __restrict__ binofs,
                                                 int* __restrict__ binfill,
                                                 int* __restrict__ perm, int M,
                                                 int fillBlocks) {
    if ((int)blockIdx.x < fillBlocks) {
        int e = blockIdx.x * 1024 + threadIdx.x;
        if (e >= E) return;
        int s = src[e], d = dst[e];
        int ds_ = deg[s], dd = deg[d];
        float dis = (ds_ > 0) ? rsqrtf((float)ds_) : 0.f;
        float did = (dd  > 0) ? rsqrtf((float)dd)  : 0.f;
        csw[rowptr[d] + rank[e]] = make_int2(s, __float_as_int(-dis * did));
    } else {
        __shared__ int lb[NBIN];
        __shared__ int lbase[NBIN];
        int t = threadIdx.x;
        lb[t] = 0;
        __syncthreads();
        int n = ((int)blockIdx.x - fillBlocks) * 1024 + t;
        int v = 0, r = 0;
        if (n < M) {
            v = deg[n] & (NBIN - 1);
            r = atomicAdd(&lb[v], 1);          // local rank within (block, bin)
        }
        __syncthreads();
        if (lb[t] > 0) lbase[t] = atomicAdd(&binfill[t], lb[t]);   // block base
        __syncthreads();
        if (n < M) perm[binofs[v] + lbase[v] + r] = n;
    }
}

// ---------------------------------------------------------------- prop -----
// bf16 features: row = 128 bf16 = 16 uint4. 16 lanes per node, uint4/lane
// (16B = coalescing sweet spot). 4 nodes per wave -> 4 independent edge
// chains; 4-wide unroll -> 16 gathers in flight per wave. (Round-9 post-
// mortem: 2 nodes/group doubled chains but halved the grid and raised VGPR
// pressure -> net regression. This 1-node/group form is the local optimum.)
// Nodes processed in degree-sorted order (perm): uniform trip counts.
// out[n] = bf16( alpha * sum_e w[e]*xin[src[e]] + beta * other[n] )

__global__ __launch_bounds__(256) void prop_k(const uint4* __restrict__ xin,
                                              const int* __restrict__ rowptr,
                                              const int2* __restrict__ csw,
                                              const int* __restrict__ perm,
                                              const uint4* __restrict__ other,
                                              float alpha, float beta,
                                              uint4* __restrict__ out, int M) {
    int gidx = (blockIdx.x * 256 + threadIdx.x) >> 4;   // sorted position
    if (gidx >= M) return;
    int g = perm[gidx];                                  // node index
    int lane = threadIdx.x & 15;                         // sub-row 16B chunk
    int e0 = rowptr[g], e1 = rowptr[g + 1];
    float a0[8], a1[8];
    #pragma unroll
    for (int c = 0; c < 8; ++c) { a0[c] = 0.f; a1[c] = 0.f; }

    int e = e0;
    for (; e + 4 <= e1; e += 4) {
        int2 p0 = csw[e], p1 = csw[e + 1], p2 = csw[e + 2], p3 = csw[e + 3];
        uint4 v0 = xin[(size_t)p0.x * 16 + lane];
        uint4 v1 = xin[(size_t)p1.x * 16 + lane];
        uint4 v2 = xin[(size_t)p2.x * 16 + lane];
        uint4 v3 = xin[(size_t)p3.x * 16 + lane];
        float w0 = __int_as_float(p0.y), w1 = __int_as_float(p1.y);
        float w2 = __int_as_float(p2.y), w3 = __int_as_float(p3.y);
        a0[0] = fmaf(w0, bflo(v0.x), a0[0]); a0[1] = fmaf(w0, bfhi(v0.x), a0[1]);
        a0[2] = fmaf(w0, bflo(v0.y), a0[2]); a0[3] = fmaf(w0, bfhi(v0.y), a0[3]);
        a0[4] = fmaf(w0, bflo(v0.z), a0[4]); a0[5] = fmaf(w0, bfhi(v0.z), a0[5]);
        a0[6] = fmaf(w0, bflo(v0.w), a0[6]); a0[7] = fmaf(w0, bfhi(v0.w), a0[7]);
        a1[0] = fmaf(w1, bflo(v1.x), a1[0]); a1[1] = fmaf(w1, bfhi(v1.x), a1[1]);
        a1[2] = fmaf(w1, bflo(v1.y), a1[2]); a1[3] = fmaf(w1, bfhi(v1.y), a1[3]);
        a1[4] = fmaf(w1, bflo(v1.z), a1[4]); a1[5] = fmaf(w1, bfhi(v1.z), a1[5]);
        a1[6] = fmaf(w1, bflo(v1.w), a1[6]); a1[7] = fmaf(w1, bfhi(v1.w), a1[7]);
        a0[0] = fmaf(w2, bflo(v2.x), a0[0]); a0[1] = fmaf(w2, bfhi(v2.x), a0[1]);
        a0[2] = fmaf(w2, bflo(v2.y), a0[2]); a0[3] = fmaf(w2, bfhi(v2.y), a0[3]);
        a0[4] = fmaf(w2, bflo(v2.z), a0[4]); a0[5] = fmaf(w2, bfhi(v2.z), a0[5]);
        a0[6] = fmaf(w2, bflo(v2.w), a0[6]); a0[7] = fmaf(w2, bfhi(v2.w), a0[7]);
        a1[0] = fmaf(w3, bflo(v3.x), a1[0]); a1[1] = fmaf(w3, bfhi(v3.x), a1[1]);
        a1[2] = fmaf(w3, bflo(v3.y), a1[2]); a1[3] = fmaf(w3, bfhi(v3.y), a1[3]);
        a1[4] = fmaf(w3, bflo(v3.z), a1[4]); a1[5] = fmaf(w3, bfhi(v3.z), a1[5]);
        a1[6] = fmaf(w3, bflo(v3.w), a1[6]); a1[7] = fmaf(w3, bfhi(v3.w), a1[7]);
    }
    for (; e < e1; ++e) {
        int2 p0 = csw[e];
        uint4 v0 = xin[(size_t)p0.x * 16 + lane];
        float w0 = __int_as_float(p0.y);
        a0[0] = fmaf(w0, bflo(v0.x), a0[0]); a0[1] = fmaf(w0, bfhi(v0.x), a0[1]);
        a0[2] = fmaf(w0, bflo(v0.y), a0[2]); a0[3] = fmaf(w0, bfhi(v0.y), a0[3]);
        a0[4] = fmaf(w0, bflo(v0.z), a0[4]); a0[5] = fmaf(w0, bfhi(v0.z), a0[5]);
        a0[6] = fmaf(w0, bflo(v0.w), a0[6]); a0[7] = fmaf(w0, bfhi(v0.w), a0[7]);
    }

    float r[8];
    #pragma unroll
    for (int c = 0; c < 8; ++c) r[c] = alpha * (a0[c] + a1[c]);
    if (beta != 0.f) {
        uint4 o = other[(size_t)g * 16 + lane];
        r[0] = fmaf(beta, bflo(o.x), r[0]); r[1] = fmaf(beta, bfhi(o.x), r[1]);
        r[2] = fmaf(beta, bflo(o.y), r[2]); r[3] = fmaf(beta, bfhi(o.y), r[3]);
        r[4] = fmaf(beta, bflo(o.z), r[4]); r[5] = fmaf(beta, bfhi(o.z), r[5]);
        r[6] = fmaf(beta, bflo(o.w), r[6]); r[7] = fmaf(beta, bfhi(o.w), r[7]);
    }
    uint4 ov;
    ov.x = (unsigned int)f2bf(r[0]) | ((unsigned int)f2bf(r[1]) << 16);
    ov.y = (unsigned int)f2bf(r[2]) | ((unsigned int)f2bf(r[3]) << 16);
    ov.z = (unsigned int)f2bf(r[4]) | ((unsigned int)f2bf(r[5]) << 16);
    ov.w = (unsigned int)f2bf(r[6]) | ((unsigned int)f2bf(r[7]) << 16);
    out[(size_t)g * 16 + lane] = ov;
}

// ---------------------------------------------------------------- GEMM -----
// MFMA bf16 GEMM: C[m0:m0+128][0:128] = sum_{p<nP} A_p @ W_p (+ bias)
// PIECE-granular double buffer: whole piece (4 A-tiles + 4 B-tiles) staged
// per iteration; next piece's 16 b128 global loads issued before the 4
// barrier-free K-steps, so HBM latency hides under a full piece of MFMAs.
// 2 barriers per piece. (Round-12 A-direct variant regressed: +32 live
// VGPRs and global A-loads on the per-piece critical path.)
// ABF:   A is bf16 (else fp32, converted during staging).
// STATS: fused per-column BatchNorm sum/sumsq (fp32, pre-rounding) -> sums.
// OBF:   write C as bf16.

template<bool ABF, bool STATS, bool OBF>
__global__ __launch_bounds__(256) void gemm_k(const void* __restrict__ A0_,
                                              const void* __restrict__ A1_,
                                              const void* __restrict__ A2_,
                                              const void* __restrict__ A3_,
                                              const void* __restrict__ A4_,
                                              const short* __restrict__ Wt,
                                              const float* __restrict__ bias,
                                              void* __restrict__ C_,
                                              float* __restrict__ sums,
                                              int M, int nP) {
    __shared__ short As[4][128 * LDP];   // whole piece of A [k-tile][row][k]
    __shared__ short Bs[4][128 * LDP];   // whole piece of B [k-tile][col][k]
    int t = threadIdx.x;
    int m0 = blockIdx.x * GEMM_BM;
    int wave = t >> 6;
    int lane = t & 63;
    int lh = lane & 15;        // fragment row/col within 16
    int kq = lane >> 4;        // k-group 0..3

    f32x4 acc[2][8];
    #pragma unroll
    for (int i = 0; i < 2; ++i)
        #pragma unroll
        for (int j = 0; j < 8; ++j) acc[i][j] = (f32x4){0.f, 0.f, 0.f, 0.f};

    const void* Aps[5] = {A0_, A1_, A2_, A3_, A4_};
    int srow = t >> 1;                 // staging row 0..127
    int skh  = (t & 1) << 4;           // staging k offset 0 or 16
    const bool rowok = (m0 + srow < M);

    // prefetch registers: one whole piece of A and B
    bf16x8 ra[4][2];                   // ABF path
    float4 rf[4][4];                   // fp32 path
    bf16x8 rb[4][2];

    auto load_piece = [&](int p) {
        const short* Wp = Wt + ((size_t)p << 14);
        #pragma unroll
        for (int kt = 0; kt < 4; ++kt) {
            const bf16x8* srcB = (const bf16x8*)&Wp[(srow << 7) + kt * KSTEP + skh];
            rb[kt][0] = srcB[0]; rb[kt][1] = srcB[1];
            if (ABF) {
                ra[kt][0] = (bf16x8){0,0,0,0,0,0,0,0}; ra[kt][1] = ra[kt][0];
                if (rowok) {
                    const bf16x8* s = (const bf16x8*)
                        &((const unsigned short*)Aps[p])[(size_t)(m0 + srow) * CH + kt * KSTEP + skh];
                    ra[kt][0] = s[0]; ra[kt][1] = s[1];
                }
            } else {
                rf[kt][0] = rf[kt][1] = rf[kt][2] = rf[kt][3] = make_float4(0.f, 0.f, 0.f, 0.f);
                if (rowok) {
                    const float4* s = (const float4*)
                        &((const float*)Aps[p])[(size_t)(m0 + srow) * CH + kt * KSTEP + skh];
                    rf[kt][0] = s[0]; rf[kt][1] = s[1]; rf[kt][2] = s[2]; rf[kt][3] = s[3];
                }
            }
        }
    };

    load_piece(0);

    for (int p = 0; p < nP; ++p) {
        __syncthreads();   // previous piece's LDS reads complete (no-op at p=0)
        // ---- dump prefetched regs -> LDS
        #pragma unroll
        for (int kt = 0; kt < 4; ++kt) {
            if (ABF) {
                *(bf16x8*)&As[kt][srow * LDP + skh]     = ra[kt][0];
                *(bf16x8*)&As[kt][srow * LDP + skh + 8] = ra[kt][1];
            } else {
                bf16x8 lo, hi;
                lo[0] = (short)f2bf(rf[kt][0].x); lo[1] = (short)f2bf(rf[kt][0].y);
                lo[2] = (short)f2bf(rf[kt][0].z); lo[3] = (short)f2bf(rf[kt][0].w);
                lo[4] = (short)f2bf(rf[kt][1].x); lo[5] = (short)f2bf(rf[kt][1].y);
                lo[6] = (short)f2bf(rf[kt][1].z); lo[7] = (short)f2bf(rf[kt][1].w);
                hi[0] = (short)f2bf(rf[kt][2].x); hi[1] = (short)f2bf(rf[kt][2].y);
                hi[2] = (short)f2bf(rf[kt][2].z); hi[3] = (short)f2bf(rf[kt][2].w);
                hi[4] = (short)f2bf(rf[kt][3].x); hi[5] = (short)f2bf(rf[kt][3].y);
                hi[6] = (short)f2bf(rf[kt][3].z); hi[7] = (short)f2bf(rf[kt][3].w);
                *(bf16x8*)&As[kt][srow * LDP + skh]     = lo;
                *(bf16x8*)&As[kt][srow * LDP + skh + 8] = hi;
            }
            *(bf16x8*)&Bs[kt][srow * LDP + skh]     = rb[kt][0];
            *(bf16x8*)&Bs[kt][srow * LDP + skh + 8] = rb[kt][1];
        }
        __syncthreads();
        // ---- issue next piece's global loads (hide under this piece's MFMAs)
        if (p + 1 < nP) load_piece(p + 1);
        // ---- 4 K-steps, barrier-free
        #pragma unroll
        for (int k = 0; k < 4; ++k) {
            bf16x8 af[2], bfr[8];
            #pragma unroll
            for (int fm = 0; fm < 2; ++fm)
                af[fm] = *(const bf16x8*)&As[k][(wave * 32 + fm * 16 + lh) * LDP + kq * 8];
            #pragma unroll
            for (int fn = 0; fn < 8; ++fn)
                bfr[fn] = *(const bf16x8*)&Bs[k][(fn * 16 + lh) * LDP + kq * 8];
            #pragma unroll
            for (int fm = 0; fm < 2; ++fm)
                #pragma unroll
                for (int fn = 0; fn < 8; ++fn)
                    acc[fm][fn] = __builtin_amdgcn_mfma_f32_16x16x32_bf16(
                        af[fm], bfr[fn], acc[fm][fn], 0, 0, 0);
        }
    }

    // ---- epilogue: row = m0 + wave*32 + fm*16 + kq*4 + j, col = fn*16 + lh
    float s_[8], q_[8];
    #pragma unroll
    for (int fn = 0; fn < 8; ++fn) { s_[fn] = 0.f; q_[fn] = 0.f; }
    float bj[8];
    #pragma unroll
    for (int fn = 0; fn < 8; ++fn) bj[fn] = bias ? bias[fn * 16 + lh] : 0.f;

    #pragma unroll
    for (int fm = 0; fm < 2; ++fm) {
        #pragma unroll
        for (int j = 0; j < 4; ++j) {
            int m = m0 + wave * 32 + fm * 16 + kq * 4 + j;
            if (m >= M) continue;
            #pragma unroll
            for (int fn = 0; fn < 8; ++fn) {
                int col = fn * 16 + lh;
                float v = acc[fm][fn][j] + bj[fn];
                if (STATS) { s_[fn] += v; q_[fn] = fmaf(v, v, q_[fn]); }
                if (OBF) ((unsigned short*)C_)[(size_t)m * CH + col] = f2bf(v);
                else     ((float*)C_)[(size_t)m * CH + col] = v;
            }
        }
    }

    if (STATS) {
        #pragma unroll
        for (int fn = 0; fn < 8; ++fn) {
            s_[fn] += __shfl_xor(s_[fn], 16); s_[fn] += __shfl_xor(s_[fn], 32);
            q_[fn] += __shfl_xor(q_[fn], 16); q_[fn] += __shfl_xor(q_[fn], 32);
        }
        float* red = (float*)&As[0][0];   // reuse As LDS: [2][4][128] floats
        __syncthreads();                  // all waves done reading As/Bs
        if (kq == 0) {
            #pragma unroll
            for (int fn = 0; fn < 8; ++fn) {
                red[(0 * 4 + wave) * 128 + fn * 16 + lh] = s_[fn];
                red[(1 * 4 + wave) * 128 + fn * 16 + lh] = q_[fn];
            }
        }
        __syncthreads();
        if (t < 128) {
            float ss = red[0 * 128 + t] + red[1 * 128 + t] + red[2 * 128 + t] + red[3 * 128 + t];
            float qq = red[4 * 128 + t] + red[5 * 128 + t] + red[6 * 128 + t] + red[7 * 128 + t];
            atomicAdd(&sums[t], ss);
            atomicAdd(&sums[128 + t], qq);
        }
    }
}

// ---------------------------------------------------------------- BN -------
// BN coef computed per block from fused stats; apply + ReLU, bf16 -> bf16

__global__ __launch_bounds__(256) void bnapply_k(const unsigned int* __restrict__ hb,
                                                 const float* __restrict__ sums,
                                                 const float* __restrict__ gamma,
                                                 const float* __restrict__ beta,
                                                 float invM,
                                                 unsigned int* __restrict__ outb, int M) {
    __shared__ float sc[128], sh[128];
    int t = threadIdx.x;
    if (t < 128) {
        float m   = sums[t] * invM;
        float var = fmaxf(sums[128 + t] * invM - m * m, 0.f);
        float s   = gamma[t] * rsqrtf(var + 1e-5f);
        sc[t] = s;
        sh[t] = beta[t] - m * s;
    }
    __syncthreads();
    int total = M * 64;
    for (int idx = blockIdx.x * blockDim.x + t; idx < total;
         idx += gridDim.x * blockDim.x) {
        int c2 = (idx & 63) * 2;
        unsigned int v = hb[idx];
        float a = fmaxf(fmaf(bflo(v), sc[c2 + 0], sh[c2 + 0]), 0.f);
        float b = fmaxf(fmaf(bfhi(v), sc[c2 + 1], sh[c2 + 1]), 0.f);
        outb[idx] = (unsigned int)f2bf(a) | ((unsigned int)f2bf(b) << 16);
    }
}

// ---------------------------------------------------------------- launch ---

extern "C" void kernel_launch(void* const* d_in, const int* in_sizes, int n_in,
                              void* d_out, int out_size, void* d_ws, size_t ws_size,
                              hipStream_t stream) {
    const float* x      = (const float*)d_in[0];
    const int*   ei     = (const int*)d_in[1];
    const float* w1     = (const float*)d_in[2];
    const float* b1     = (const float*)d_in[3];
    const float* w2     = (const float*)d_in[4];
    const float* b2     = (const float*)d_in[5];
    const float* w3     = (const float*)d_in[6];
    const float* b3     = (const float*)d_in[7];
    const float* gamma1 = (const float*)d_in[8];
    const float* beta1  = (const float*)d_in[9];
    const float* gamma2 = (const float*)d_in[10];
    const float* beta2  = (const float*)d_in[11];
    float* out = (float*)d_out;

    const int M = in_sizes[0] / CH;   // 50000 nodes
    const int E = in_sizes[1] / 2;    // 600000 edges
    const int* srcp = ei;
    const int* dstp = ei + E;

    size_t off = 0;
    auto alloc = [&](size_t bytes) {
        void* p = (char*)d_ws + off;
        off += (bytes + 255) & ~(size_t)255;
        return p;
    };
    // zeroed-region first (one memset covers deg|bins|binfill|bnsumsA|bnsumsB)
    int*   degi    = (int*)  alloc((size_t)M * 4);
    int*   bins    = (int*)  alloc(NBIN * 4);
    int*   binfill = (int*)  alloc(NBIN * 4);
    float* bnsumsA = (float*)alloc(1024);
    float* bnsumsB = (float*)alloc(1024);
    size_t zero_bytes = off;
    unsigned int* PB0 = (unsigned int*)alloc((size_t)M * CH * 2);  // bf16 feat
    unsigned int* PB1 = (unsigned int*)alloc((size_t)M * CH * 2);
    unsigned int* PB2 = (unsigned int*)alloc((size_t)M * CH * 2);
    unsigned int* PB3 = (unsigned int*)alloc((size_t)M * CH * 2);
    unsigned int* PB4 = (unsigned int*)alloc((size_t)M * CH * 2);
    unsigned int* Hb  = (unsigned int*)alloc((size_t)M * CH * 2);  // bf16 pre-BN
    int2*  csw     = (int2*) alloc((size_t)E * 8);
    int*   rank    = (int*)  alloc((size_t)E * 4);
    int*   rowptr  = (int*)  alloc((size_t)(M + 1) * 4);
    int*   bsum    = (int*)  alloc(4096);
    int*   binofs  = (int*)  alloc(NBIN * 4);
    int*   perm    = (int*)  alloc((size_t)M * 4);
    short* Wt      = (short*)alloc((size_t)9 * CH * CH * 2);       // 9 pieces
    (void)ws_size; (void)n_in; (void)out_size;

    const int nb = (M + 1023) / 1024;
    const int gb = (M + GEMM_BM - 1) / GEMM_BM;
    const int pgrid = (M + 15) / 16;   // 16 nodes per 256-thread block
    const int histBlocks = (E + 255) / 256;
    const int wBlocks = (9 * 16384 + 255) / 256;
    const int fillBlocks = (E + 1023) / 1024;

    // ---- graph setup: degree+rank+wconv -> rowptr(+bins) -> CSR+perm
    hipMemsetAsync(degi, 0, zero_bytes, stream);
    setup1_k<<<histBlocks + wBlocks, 256, 0, stream>>>(dstp, degi, rank, E,
                                                       w1, w2, w3, Wt, 9 * 16384,
                                                       histBlocks);
    scan_partial_k<<<nb, 1024, 0, stream>>>(degi, rowptr, bsum, bins, M);
    scan_add2_k<<<nb, 1024, 0, stream>>>(rowptr, bsum, nb, M, bins, binofs);
    setup2_k<<<fillBlocks + nb, 1024, 0, stream>>>(srcp, dstp, rank, rowptr, degi,
                                                   csw, E, binofs, binfill, perm, M,
                                                   fillBlocks);

    // ---- layer 1: Hb = bf16(x @ W1 + b1) (fp32 stats fused) ; BN+ReLU -> PB0
    gemm_k<false, true, true><<<gb, 256, 0, stream>>>(x, nullptr, nullptr, nullptr,
                                                      nullptr, Wt, b1, Hb, bnsumsA, M, 1);
    bnapply_k<<<2048, 256, 0, stream>>>(Hb, bnsumsA, gamma1, beta1, 1.f / (float)M, PB0, M);

    // ---- layer 2 (K=3): Tx0=PB0, Tx1=PB1, Tx2=PB2 ; BN+ReLU -> PB0
    prop_k<<<pgrid, 256, 0, stream>>>((const uint4*)PB0, rowptr, csw, perm,
                                      (const uint4*)PB0, 1.f, 0.f, (uint4*)PB1, M);
    prop_k<<<pgrid, 256, 0, stream>>>((const uint4*)PB1, rowptr, csw, perm,
                                      (const uint4*)PB0, 2.f, -1.f, (uint4*)PB2, M);
    gemm_k<true, true, true><<<gb, 256, 0, stream>>>(PB0, PB1, PB2, nullptr, nullptr,
                                                     Wt + (1 << 14), b2, Hb, bnsumsB, M, 3);
    bnapply_k<<<2048, 256, 0, stream>>>(Hb, bnsumsB, gamma2, beta2, 1.f / (float)M, PB0, M);

    // ---- layer 3 (K=5): Tx0=PB0 ... Tx4=PB4, single nP=5 GEMM -> out (fp32)
    prop_k<<<pgrid, 256, 0, stream>>>((const uint4*)PB0, rowptr, csw, perm,
                                      (const uint4*)PB0, 1.f, 0.f, (uint4*)PB1, M);
    prop_k<<<pgrid, 256, 0, stream>>>((const uint4*)PB1, rowptr, csw, perm,
                                      (const uint4*)PB0, 2.f, -1.f, (uint4*)PB2, M);
    prop_k<<<pgrid, 256, 0, stream>>>((const uint4*)PB2, rowptr, csw, perm,
                                      (const uint4*)PB1, 2.f, -1.f, (uint4*)PB3, M);
    prop_k<<<pgrid, 256, 0, stream>>>((const uint4*)PB3, rowptr, csw, perm,
                                      (const uint4*)PB2, 2.f, -1.f, (uint4*)PB4, M);
    gemm_k<true, false, false><<<gb, 256, 0, stream>>>(PB0, PB1, PB2, PB3, PB4,
                                                       Wt + (4 << 14), b3, out, nullptr, M, 5);
}